// Round 16
// baseline (189.289 us; speedup 1.0000x reference)
//
#include <hip/hip_runtime.h>
#include <hip/hip_bf16.h>

constexpr int Nn = 100000;   // nodes
constexpr int Ee = 1600000;  // edges
constexpr int Fd = 128;      // in features
constexpr int Dd = 64;       // out features
constexpr float ALPHA = 0.2f;

constexpr int BSH   = 6;                    // 64 rows per bucket (spmm block == bucket)
constexpr int NBK   = (Nn + 63) >> 6;       // 1563 buckets
constexpr int BSLK  = 2048;                 // slack entries per bucket (mean fill 1023, +32 sigma)
constexpr int BINB  = 1024;                 // binning blocks (1563 edges each, mean 1/bucket)
constexpr int BCAP  = 4;                    // LDS slots per bucket per bin block (~0.4% spill, correct path)
constexpr int GEMB  = (Nn + 63) / 64;       // 1563 gemm node-tiles
constexpr int HCAP  = 1536;                 // spmm per-bucket LDS edge cap (mean 1023, +16 sigma)
constexpr int HPW   = 138;                  // wt LDS pitch: bank step 5 (coprime 32, conflict-free)

typedef __attribute__((ext_vector_type(8))) short bf16x8;   // 8 bf16 (4 VGPRs)
typedef __attribute__((ext_vector_type(4))) float f32x4;    // MFMA accumulator

__device__ __forceinline__ unsigned short f2bf(float f) {  // RTNE
    unsigned int u = __float_as_uint(f);
    u += 0x7fffu + ((u >> 16) & 1u);
    return (unsigned short)(u >> 16);
}
__device__ __forceinline__ float bflo(unsigned int u) {  // low bf16 of dword
    return __uint_as_float(u << 16);
}
__device__ __forceinline__ float bfhi(unsigned int u) {  // high bf16 of dword
    return __uint_as_float(u & 0xFFFF0000u);
}

// ---------------- bucket write-pointer init ----------------
__global__ void bwp_init(int* __restrict__ bwp)
{
    int b = blockIdx.x * 256 + threadIdx.x;
    if (b < NBK) bwp[b] = b * BSLK;
}

// ============ fused bin + gemm: independent phases share one grid ============
// blocks [0, BINB)          : LDS-binned staging of packed 4B edges
//                             entry = ((r & 63) << 17) | c   (c < 2^17)
//                             1024 blocks (1563 edges each): half the serial
//                             chain of R15; (off,cnt) packed into one LDS array
// blocks [BINB, BINB+GEMB)  : MFMA GEMM (R13's measured gemm body: direct-x
//                             fragments + LDS W at HPW=138, one barrier)
// Union LDS 30.5 KB -> 5 blocks/CU (was 37.5 KB / 4).
__global__ __launch_bounds__(256, 5) void bin_gemm(
    const int* __restrict__ rows, const int* __restrict__ cols,
    int* __restrict__ bwp, unsigned int* __restrict__ binned,
    const float* __restrict__ x, const float* __restrict__ W,
    const float* __restrict__ a_row, const float* __restrict__ a_col,
    unsigned short* __restrict__ h, float* __restrict__ ar, float* __restrict__ ac)
{
    __shared__ union {
        struct { unsigned int buf[NBK * BCAP]; int lcnt[NBK]; } s;     // 30.5 KB
        struct { unsigned short wt[64 * HPW]; float as_[2 * Dd]; } g;  // 18.1 KB
    } sm;

    const int tid = threadIdx.x;

    if (blockIdx.x < BINB) {
        // ---------------- binning path ----------------
        for (int b = tid; b < NBK; b += 256) sm.s.lcnt[b] = 0;
        __syncthreads();

        const int per = (Ee + BINB - 1) / BINB;   // 1563
        const int e0 = blockIdx.x * per;
        const int e1 = min(e0 + per, Ee);

        for (int base = e0; base < e1; base += 1024) {
            int rr[4], cc[4];
            bool vv[4];
            #pragma unroll
            for (int u = 0; u < 4; ++u) {
                int e = base + u * 256 + tid;
                bool v = e < e1;
                int idx = v ? e : e0;
                rr[u] = rows[idx]; cc[u] = cols[idx]; vv[u] = v;
            }
            #pragma unroll
            for (int u = 0; u < 4; ++u) {
                if (vv[u]) {
                    int b = rr[u] >> BSH;
                    unsigned int pe = ((unsigned)(rr[u] & 63) << 17) | (unsigned)cc[u];
                    int pos = atomicAdd(&sm.s.lcnt[b], 1);
                    if (pos < BCAP) sm.s.buf[b * BCAP + pos] = pe;
                    else {  // spill (~0.4%): direct append, correct path
                        int slot = atomicAdd(&bwp[b], 1);
                        if (slot < (b + 1) * BSLK) binned[slot] = pe;
                    }
                }
            }
        }
        __syncthreads();
        // reserve bucket slots; pack (off,cnt) into lcnt (each b owned by one thread)
        for (int b = tid; b < NBK; b += 256) {
            int cntv = min(sm.s.lcnt[b], BCAP);
            int off = 0;
            if (cntv) {
                off = atomicAdd(&bwp[b], cntv) - b * BSLK;
                off = min(max(off, 0), 65535);
            }
            sm.s.lcnt[b] = (off << 16) | cntv;
        }
        __syncthreads();
        // parallel writeout: 4 lanes per bucket, 64 buckets per pass
        for (int b0 = 0; b0 < NBK; b0 += 64) {
            int b = b0 + (tid >> 2);
            int i = tid & 3;
            if (b < NBK) {
                unsigned int pk = (unsigned)sm.s.lcnt[b];
                int cnt = (int)(pk & 0xFFFFu);
                int off = (int)(pk >> 16);
                if (i < cnt) {
                    int slot = b * BSLK + off + i;
                    if (slot < (b + 1) * BSLK) binned[slot] = sm.s.buf[b * BCAP + i];
                }
            }
        }
    } else {
        // ---------------- gemm path ----------------
        #pragma unroll 4
        for (int it = 0; it < 32; ++it) {
            int idx = tid + 256 * it;
            int k = idx >> 6, d = idx & 63;
            sm.g.wt[d * HPW + k] = f2bf(W[idx]);
        }
        if (tid < 2 * Dd) sm.g.as_[tid] = (tid < Dd) ? a_row[tid] : a_col[tid - Dd];
        __syncthreads();

        const int lane = tid & 63;
        const int wid  = tid >> 6;
        const int nlo  = lane & 15;
        const int quad = lane >> 4;

        const int node0 = (blockIdx.x - BINB) * 64;
        const int row = node0 + wid * 16 + nlo;      // this lane's x row
        const float* xr = x + (size_t)row * Fd + quad * 8;

        // direct global->VGPR fragment loads: per ks, wave reads 16 rows x 128B contiguous
        float4 xa[8];
        if (row < Nn) {
            #pragma unroll
            for (int ks = 0; ks < 4; ++ks) {
                xa[2 * ks + 0] = *(const float4*)(xr + ks * 32);
                xa[2 * ks + 1] = *(const float4*)(xr + ks * 32 + 4);
            }
        } else {
            #pragma unroll
            for (int u = 0; u < 8; ++u) xa[u] = make_float4(0.f, 0.f, 0.f, 0.f);
        }

        f32x4 acc[4] = {{0.f,0.f,0.f,0.f},{0.f,0.f,0.f,0.f},{0.f,0.f,0.f,0.f},{0.f,0.f,0.f,0.f}};

        #pragma unroll
        for (int ks = 0; ks < 4; ++ks) {
            float4 lo = xa[2 * ks + 0], hi = xa[2 * ks + 1];
            bf16x8 a;
            a[0] = (short)f2bf(lo.x); a[1] = (short)f2bf(lo.y);
            a[2] = (short)f2bf(lo.z); a[3] = (short)f2bf(lo.w);
            a[4] = (short)f2bf(hi.x); a[5] = (short)f2bf(hi.y);
            a[6] = (short)f2bf(hi.z); a[7] = (short)f2bf(hi.w);
            #pragma unroll
            for (int t = 0; t < 4; ++t) {
                bf16x8 b = *(const bf16x8*)&sm.g.wt[(t * 16 + nlo) * HPW + quad * 8 + ks * 32];
                acc[t] = __builtin_amdgcn_mfma_f32_16x16x32_bf16(a, b, acc[t], 0, 0, 0);
            }
        }

        #pragma unroll
        for (int r = 0; r < 4; ++r) {
            int node = node0 + wid * 16 + quad * 4 + r;
            float pr = 0.f, pc = 0.f;
            #pragma unroll
            for (int t = 0; t < 4; ++t) {
                float v = acc[t][r];
                pr = fmaf(v, sm.g.as_[t * 16 + nlo], pr);
                pc = fmaf(v, sm.g.as_[Dd + t * 16 + nlo], pc);
            }
            #pragma unroll
            for (int o = 1; o < 16; o <<= 1) {
                pr += __shfl_xor(pr, o, 64);
                pc += __shfl_xor(pc, o, 64);
            }
            if (node < Nn) {
                #pragma unroll
                for (int t = 0; t < 4; ++t)
                    h[(size_t)node * Dd + t * 16 + nlo] = f2bf(acc[t][r]);
                if (nlo == 0) { ar[node] = pr; ac[node] = pc; }
            }
        }
    }
}

// ------------- spmm_fused: register scan + row-owned 8-lane broadcast gather -------------
// (byte-identical to R13's measured 40.8 us version)
__global__ __launch_bounds__(256, 4) void spmm_fused(
    const unsigned int* __restrict__ binned, const int* __restrict__ bwp,
    const float* __restrict__ ar, const float* __restrict__ ac,
    const unsigned short* __restrict__ h, float* __restrict__ out)
{
    __shared__ float2 lce[HCAP];     // 12.3 KB ordered (col, ex)
    __shared__ int   cnt[64];
    __shared__ int   wp[64];
    __shared__ int   loff[65];
    __shared__ float lar[64];

    const int tid   = threadIdx.x;
    const int b     = blockIdx.x;
    const int node0 = b << BSH;
    const int base  = b * BSLK;
    const int n     = min(bwp[b] - base, BSLK);

    if (tid < 64) {
        cnt[tid] = 0;
        int node = node0 + tid;
        lar[tid] = (node < Nn) ? ar[node] : 0.f;
    }
    __syncthreads();

    // pass A: coalesced scan into registers (skip upper half when n <= 1024)
    unsigned int pe_r[8];
    float av[8];
    float ex_r[8];
    #pragma unroll
    for (int u = 0; u < 4; ++u) {
        int s = (u << 8) + tid;
        unsigned int pe = binned[base + s];
        pe_r[u] = (s < n) ? pe : 0xFFFFFFFFu;
    }
    if (n > 1024) {
        #pragma unroll
        for (int u = 4; u < 8; ++u) {
            int s = (u << 8) + tid;
            unsigned int pe = binned[base + s];
            pe_r[u] = (s < n) ? pe : 0xFFFFFFFFu;
        }
    } else {
        #pragma unroll
        for (int u = 4; u < 8; ++u) pe_r[u] = 0xFFFFFFFFu;
    }
    #pragma unroll
    for (int u = 0; u < 8; ++u) {
        int c = (int)(pe_r[u] & 0x1FFFFu);
        av[u] = ac[min(c, Nn - 1)];             // 8 gathers in flight, L2-hot
    }
    #pragma unroll
    for (int u = 0; u < 8; ++u) {
        unsigned int rl = pe_r[u] >> 17;        // [0,64) valid, huge for invalid
        float sc = lar[rl & 63u] + av[u];
        sc = sc > 0.f ? sc : ALPHA * sc;
        ex_r[u] = __expf(sc);
        if (rl < 64u) atomicAdd(&cnt[rl], 1);
    }
    __syncthreads();

    // wave-0 exclusive scan of 64 counters
    if (tid < 64) {
        int v = cnt[tid];
        int incl = v;
        #pragma unroll
        for (int o = 1; o < 64; o <<= 1) {
            int y = __shfl_up(incl, o, 64);
            if (tid >= o) incl += y;
        }
        loff[tid] = incl - v;
        wp[tid]   = incl - v;
        if (tid == 63) loff[64] = incl;
    }
    __syncthreads();

    // pass B: scatter ordered (col, ex) from registers
    #pragma unroll
    for (int u = 0; u < 8; ++u) {
        unsigned int rl = pe_r[u] >> 17;
        if (rl < 64u) {
            int pos = atomicAdd(&wp[rl], 1);
            if (pos < HCAP)
                lce[pos] = make_float2(__int_as_float((int)(pe_r[u] & 0x1FFFFu)), ex_r[u]);
        }
    }
    __syncthreads();

    // pass 3: 32 groups x 8 lanes; lane lq owns feats [lq*8, lq*8+8)
    const int grp = tid >> 3, lq = tid & 7;
    const uint4* h16 = (const uint4*)h;   // row = 8 uint4 (128 B)
    #pragma unroll
    for (int i = 0; i < 2; ++i) {
        int rl = grp * 2 + i;
        int node = node0 + rl;
        if (node >= Nn) break;
        int s0 = min(loff[rl],     HCAP);       // defensive clamp (HCAP overflow)
        int s1 = min(loff[rl + 1], HCAP);
        float a0 = 0.f, a1 = 0.f, a2 = 0.f, a3 = 0.f;
        float a4 = 0.f, a5 = 0.f, a6 = 0.f, a7 = 0.f;
        float wsum = 0.f;
        int j = s0;
        for (; j + 8 <= s1; j += 8) {
            float2 p[8];
            uint4 hv[8];
            #pragma unroll
            for (int u = 0; u < 8; ++u) p[u] = lce[j + u];            // broadcast
            #pragma unroll
            for (int u = 0; u < 8; ++u)
                hv[u] = h16[(size_t)__float_as_int(p[u].x) * 8 + lq]; // 8 in flight
            #pragma unroll
            for (int u = 0; u < 8; ++u) {
                float w = p[u].y;
                wsum += w;
                a0 = fmaf(w, bflo(hv[u].x), a0); a1 = fmaf(w, bfhi(hv[u].x), a1);
                a2 = fmaf(w, bflo(hv[u].y), a2); a3 = fmaf(w, bfhi(hv[u].y), a3);
                a4 = fmaf(w, bflo(hv[u].z), a4); a5 = fmaf(w, bfhi(hv[u].z), a5);
                a6 = fmaf(w, bflo(hv[u].w), a6); a7 = fmaf(w, bfhi(hv[u].w), a7);
            }
        }
        for (; j < s1; ++j) {
            float2 p = lce[j];
            float w = p.y;
            wsum += w;
            uint4 hv = h16[(size_t)__float_as_int(p.x) * 8 + lq];
            a0 = fmaf(w, bflo(hv.x), a0); a1 = fmaf(w, bfhi(hv.x), a1);
            a2 = fmaf(w, bflo(hv.y), a2); a3 = fmaf(w, bfhi(hv.y), a3);
            a4 = fmaf(w, bflo(hv.z), a4); a5 = fmaf(w, bfhi(hv.z), a5);
            a6 = fmaf(w, bflo(hv.w), a6); a7 = fmaf(w, bfhi(hv.w), a7);
        }
        float inv = (s1 > s0) ? 1.f / wsum : 0.f;
        float4 o0 = make_float4(a0 * inv, a1 * inv, a2 * inv, a3 * inv);
        float4 o1 = make_float4(a4 * inv, a5 * inv, a6 * inv, a7 * inv);
        ((float4*)out)[(size_t)node * 16 + lq * 2 + 0] = o0;
        ((float4*)out)[(size_t)node * 16 + lq * 2 + 1] = o1;
    }
}

// ---------------- launch ----------------
extern "C" void kernel_launch(void* const* d_in, const int* in_sizes, int n_in,
                              void* d_out, int out_size, void* d_ws, size_t ws_size,
                              hipStream_t stream)
{
    const float* x     = (const float*)d_in[0];
    const int*   rows  = (const int*)d_in[1];
    const int*   cols  = (const int*)d_in[2];
    const float* W     = (const float*)d_in[3];
    const float* a_row = (const float*)d_in[4];
    const float* a_col = (const float*)d_in[5];
    float* out = (float*)d_out;

    char* ws = (char*)d_ws;
    size_t o = 0;
    unsigned short* h = (unsigned short*)(ws + o); o += (size_t)Nn * Dd * 2;  // 12.8 MB
    float* ar   = (float*)(ws + o); o += (size_t)Nn * 4;
    float* ac   = (float*)(ws + o); o += (size_t)Nn * 4;
    int*   bwp  = (int*)(ws + o);   o += 2048 * 4;
    unsigned int* binned = (unsigned int*)(ws + o); o += (size_t)NBK * BSLK * 4; // 12.8 MB

    bwp_init<<<7, 256, 0, stream>>>(bwp);
    bin_gemm<<<BINB + GEMB, 256, 0, stream>>>(rows, cols, bwp, binned,
                                              x, W, a_row, a_col, h, ar, ac);
    spmm_fused<<<NBK, 256, 0, stream>>>(binned, bwp, ar, ac, h, out);
}

// Round 17
// 170.770 us; speedup vs baseline: 1.1084x; 1.1084x over previous
//
#include <hip/hip_runtime.h>
#include <hip/hip_bf16.h>

constexpr int Nn = 100000;   // nodes
constexpr int Ee = 1600000;  // edges
constexpr int Fd = 128;      // in features
constexpr int Dd = 64;       // out features
constexpr float ALPHA = 0.2f;

constexpr int BSH   = 6;                    // 64 rows per bucket (spmm block == bucket)
constexpr int NBK   = (Nn + 63) >> 6;       // 1563 buckets
constexpr int BSLK  = 2048;                 // slack entries per bucket (mean fill 1023, +32 sigma)
constexpr int BINB  = 512;                  // binning blocks (3125 edges each, mean 2/bucket)
constexpr int BCAP  = 4;                    // LDS slots per bucket per bin block (~5% spill, correct path)
constexpr int GEMB  = (Nn + 63) / 64;       // 1563 gemm node-tiles
constexpr int HCAP  = 1536;                 // spmm per-bucket LDS edge cap (mean 1023, +16 sigma)
constexpr int HPW   = 138;                  // wt LDS pitch: bank step 5 (coprime 32, conflict-free)

typedef __attribute__((ext_vector_type(8))) short bf16x8;   // 8 bf16 (4 VGPRs)
typedef __attribute__((ext_vector_type(4))) float f32x4;    // MFMA accumulator

__device__ __forceinline__ unsigned short f2bf(float f) {  // RTNE
    unsigned int u = __float_as_uint(f);
    u += 0x7fffu + ((u >> 16) & 1u);
    return (unsigned short)(u >> 16);
}
__device__ __forceinline__ float bflo(unsigned int u) {  // low bf16 of dword
    return __uint_as_float(u << 16);
}
__device__ __forceinline__ float bfhi(unsigned int u) {  // high bf16 of dword
    return __uint_as_float(u & 0xFFFF0000u);
}

// ---------------- bucket write-pointer init ----------------
__global__ void bwp_init(int* __restrict__ bwp)
{
    int b = blockIdx.x * 256 + threadIdx.x;
    if (b < NBK) bwp[b] = b * BSLK;
}

// ============ fused bin + gemm: independent phases share one grid ============
// blocks [0, BINB)          : LDS-binned staging of packed 4B edges
//                             entry = ((r & 63) << 17) | c   (c < 2^17)
//                             (R13's measured bin body: 4-edge batched loads)
// blocks [BINB, BINB+GEMB)  : MFMA GEMM (R13's measured gemm body: direct-x
//                             fragments + LDS W at HPW=138, one barrier)
// Rationale: bin is latency-bound at ~2 blocks/CU; gemm is a streaming kernel.
// Co-residency lets gemm fill the issue slots bin leaves idle (R15: 171.5 us).
// NOTE: BINB=512 is measured-optimal — 1024 doubled per-block fixed costs
// (bucket-counter scan + 25-pass writeout) and fragmented HBM writes (R16).
__global__ __launch_bounds__(256, 4) void bin_gemm(
    const int* __restrict__ rows, const int* __restrict__ cols,
    int* __restrict__ bwp, unsigned int* __restrict__ binned,
    const float* __restrict__ x, const float* __restrict__ W,
    const float* __restrict__ a_row, const float* __restrict__ a_col,
    unsigned short* __restrict__ h, float* __restrict__ ar, float* __restrict__ ac)
{
    __shared__ union {
        struct { unsigned int buf[NBK * BCAP]; int lcnt[NBK]; int lbase[NBK]; } s; // 37.5 KB
        struct { unsigned short wt[64 * HPW]; float as_[2 * Dd]; } g;              // 18.1 KB
    } sm;

    const int tid = threadIdx.x;

    if (blockIdx.x < BINB) {
        // ---------------- binning path ----------------
        for (int b = tid; b < NBK; b += 256) sm.s.lcnt[b] = 0;
        __syncthreads();

        const int per = (Ee + BINB - 1) / BINB;   // 3125
        const int e0 = blockIdx.x * per;
        const int e1 = min(e0 + per, Ee);

        for (int base = e0; base < e1; base += 1024) {
            int rr[4], cc[4];
            bool vv[4];
            #pragma unroll
            for (int u = 0; u < 4; ++u) {
                int e = base + u * 256 + tid;
                bool v = e < e1;
                int idx = v ? e : e0;
                rr[u] = rows[idx]; cc[u] = cols[idx]; vv[u] = v;
            }
            #pragma unroll
            for (int u = 0; u < 4; ++u) {
                if (vv[u]) {
                    int b = rr[u] >> BSH;
                    unsigned int pe = ((unsigned)(rr[u] & 63) << 17) | (unsigned)cc[u];
                    int pos = atomicAdd(&sm.s.lcnt[b], 1);
                    if (pos < BCAP) sm.s.buf[b * BCAP + pos] = pe;
                    else {  // spill (~5%): direct append, correct path
                        int slot = atomicAdd(&bwp[b], 1);
                        if (slot < (b + 1) * BSLK) binned[slot] = pe;
                    }
                }
            }
        }
        __syncthreads();
        for (int b = tid; b < NBK; b += 256) {
            int c = min(sm.s.lcnt[b], BCAP);
            sm.s.lbase[b] = c ? atomicAdd(&bwp[b], c) : 0;
        }
        __syncthreads();
        // parallel writeout: 4 lanes per bucket, 64 buckets per pass
        for (int b0 = 0; b0 < NBK; b0 += 64) {
            int b = b0 + (tid >> 2);
            int i = tid & 3;
            if (b < NBK && i < min(sm.s.lcnt[b], BCAP)) {
                int slot = sm.s.lbase[b] + i;
                if (slot < (b + 1) * BSLK) binned[slot] = sm.s.buf[b * BCAP + i];
            }
        }
    } else {
        // ---------------- gemm path ----------------
        #pragma unroll 4
        for (int it = 0; it < 32; ++it) {
            int idx = tid + 256 * it;
            int k = idx >> 6, d = idx & 63;
            sm.g.wt[d * HPW + k] = f2bf(W[idx]);
        }
        if (tid < 2 * Dd) sm.g.as_[tid] = (tid < Dd) ? a_row[tid] : a_col[tid - Dd];
        __syncthreads();

        const int lane = tid & 63;
        const int wid  = tid >> 6;
        const int nlo  = lane & 15;
        const int quad = lane >> 4;

        const int node0 = (blockIdx.x - BINB) * 64;
        const int row = node0 + wid * 16 + nlo;      // this lane's x row
        const float* xr = x + (size_t)row * Fd + quad * 8;

        // direct global->VGPR fragment loads: per ks, wave reads 16 rows x 128B contiguous
        float4 xa[8];
        if (row < Nn) {
            #pragma unroll
            for (int ks = 0; ks < 4; ++ks) {
                xa[2 * ks + 0] = *(const float4*)(xr + ks * 32);
                xa[2 * ks + 1] = *(const float4*)(xr + ks * 32 + 4);
            }
        } else {
            #pragma unroll
            for (int u = 0; u < 8; ++u) xa[u] = make_float4(0.f, 0.f, 0.f, 0.f);
        }

        f32x4 acc[4] = {{0.f,0.f,0.f,0.f},{0.f,0.f,0.f,0.f},{0.f,0.f,0.f,0.f},{0.f,0.f,0.f,0.f}};

        #pragma unroll
        for (int ks = 0; ks < 4; ++ks) {
            float4 lo = xa[2 * ks + 0], hi = xa[2 * ks + 1];
            bf16x8 a;
            a[0] = (short)f2bf(lo.x); a[1] = (short)f2bf(lo.y);
            a[2] = (short)f2bf(lo.z); a[3] = (short)f2bf(lo.w);
            a[4] = (short)f2bf(hi.x); a[5] = (short)f2bf(hi.y);
            a[6] = (short)f2bf(hi.z); a[7] = (short)f2bf(hi.w);
            #pragma unroll
            for (int t = 0; t < 4; ++t) {
                bf16x8 b = *(const bf16x8*)&sm.g.wt[(t * 16 + nlo) * HPW + quad * 8 + ks * 32];
                acc[t] = __builtin_amdgcn_mfma_f32_16x16x32_bf16(a, b, acc[t], 0, 0, 0);
            }
        }

        #pragma unroll
        for (int r = 0; r < 4; ++r) {
            int node = node0 + wid * 16 + quad * 4 + r;
            float pr = 0.f, pc = 0.f;
            #pragma unroll
            for (int t = 0; t < 4; ++t) {
                float v = acc[t][r];
                pr = fmaf(v, sm.g.as_[t * 16 + nlo], pr);
                pc = fmaf(v, sm.g.as_[Dd + t * 16 + nlo], pc);
            }
            #pragma unroll
            for (int o = 1; o < 16; o <<= 1) {
                pr += __shfl_xor(pr, o, 64);
                pc += __shfl_xor(pc, o, 64);
            }
            if (node < Nn) {
                #pragma unroll
                for (int t = 0; t < 4; ++t)
                    h[(size_t)node * Dd + t * 16 + nlo] = f2bf(acc[t][r]);
                if (nlo == 0) { ar[node] = pr; ac[node] = pc; }
            }
        }
    }
}

// ------------- spmm_fused: register scan + row-owned 8-lane broadcast gather -------------
// (byte-identical to R13's measured 40.8 us version)
__global__ __launch_bounds__(256, 4) void spmm_fused(
    const unsigned int* __restrict__ binned, const int* __restrict__ bwp,
    const float* __restrict__ ar, const float* __restrict__ ac,
    const unsigned short* __restrict__ h, float* __restrict__ out)
{
    __shared__ float2 lce[HCAP];     // 12.3 KB ordered (col, ex)
    __shared__ int   cnt[64];
    __shared__ int   wp[64];
    __shared__ int   loff[65];
    __shared__ float lar[64];

    const int tid   = threadIdx.x;
    const int b     = blockIdx.x;
    const int node0 = b << BSH;
    const int base  = b * BSLK;
    const int n     = min(bwp[b] - base, BSLK);

    if (tid < 64) {
        cnt[tid] = 0;
        int node = node0 + tid;
        lar[tid] = (node < Nn) ? ar[node] : 0.f;
    }
    __syncthreads();

    // pass A: coalesced scan into registers (skip upper half when n <= 1024)
    unsigned int pe_r[8];
    float av[8];
    float ex_r[8];
    #pragma unroll
    for (int u = 0; u < 4; ++u) {
        int s = (u << 8) + tid;
        unsigned int pe = binned[base + s];
        pe_r[u] = (s < n) ? pe : 0xFFFFFFFFu;
    }
    if (n > 1024) {
        #pragma unroll
        for (int u = 4; u < 8; ++u) {
            int s = (u << 8) + tid;
            unsigned int pe = binned[base + s];
            pe_r[u] = (s < n) ? pe : 0xFFFFFFFFu;
        }
    } else {
        #pragma unroll
        for (int u = 4; u < 8; ++u) pe_r[u] = 0xFFFFFFFFu;
    }
    #pragma unroll
    for (int u = 0; u < 8; ++u) {
        int c = (int)(pe_r[u] & 0x1FFFFu);
        av[u] = ac[min(c, Nn - 1)];             // 8 gathers in flight, L2-hot
    }
    #pragma unroll
    for (int u = 0; u < 8; ++u) {
        unsigned int rl = pe_r[u] >> 17;        // [0,64) valid, huge for invalid
        float sc = lar[rl & 63u] + av[u];
        sc = sc > 0.f ? sc : ALPHA * sc;
        ex_r[u] = __expf(sc);
        if (rl < 64u) atomicAdd(&cnt[rl], 1);
    }
    __syncthreads();

    // wave-0 exclusive scan of 64 counters
    if (tid < 64) {
        int v = cnt[tid];
        int incl = v;
        #pragma unroll
        for (int o = 1; o < 64; o <<= 1) {
            int y = __shfl_up(incl, o, 64);
            if (tid >= o) incl += y;
        }
        loff[tid] = incl - v;
        wp[tid]   = incl - v;
        if (tid == 63) loff[64] = incl;
    }
    __syncthreads();

    // pass B: scatter ordered (col, ex) from registers
    #pragma unroll
    for (int u = 0; u < 8; ++u) {
        unsigned int rl = pe_r[u] >> 17;
        if (rl < 64u) {
            int pos = atomicAdd(&wp[rl], 1);
            if (pos < HCAP)
                lce[pos] = make_float2(__int_as_float((int)(pe_r[u] & 0x1FFFFu)), ex_r[u]);
        }
    }
    __syncthreads();

    // pass 3: 32 groups x 8 lanes; lane lq owns feats [lq*8, lq*8+8)
    const int grp = tid >> 3, lq = tid & 7;
    const uint4* h16 = (const uint4*)h;   // row = 8 uint4 (128 B)
    #pragma unroll
    for (int i = 0; i < 2; ++i) {
        int rl = grp * 2 + i;
        int node = node0 + rl;
        if (node >= Nn) break;
        int s0 = min(loff[rl],     HCAP);       // defensive clamp (HCAP overflow)
        int s1 = min(loff[rl + 1], HCAP);
        float a0 = 0.f, a1 = 0.f, a2 = 0.f, a3 = 0.f;
        float a4 = 0.f, a5 = 0.f, a6 = 0.f, a7 = 0.f;
        float wsum = 0.f;
        int j = s0;
        for (; j + 8 <= s1; j += 8) {
            float2 p[8];
            uint4 hv[8];
            #pragma unroll
            for (int u = 0; u < 8; ++u) p[u] = lce[j + u];            // broadcast
            #pragma unroll
            for (int u = 0; u < 8; ++u)
                hv[u] = h16[(size_t)__float_as_int(p[u].x) * 8 + lq]; // 8 in flight
            #pragma unroll
            for (int u = 0; u < 8; ++u) {
                float w = p[u].y;
                wsum += w;
                a0 = fmaf(w, bflo(hv[u].x), a0); a1 = fmaf(w, bfhi(hv[u].x), a1);
                a2 = fmaf(w, bflo(hv[u].y), a2); a3 = fmaf(w, bfhi(hv[u].y), a3);
                a4 = fmaf(w, bflo(hv[u].z), a4); a5 = fmaf(w, bfhi(hv[u].z), a5);
                a6 = fmaf(w, bflo(hv[u].w), a6); a7 = fmaf(w, bfhi(hv[u].w), a7);
            }
        }
        for (; j < s1; ++j) {
            float2 p = lce[j];
            float w = p.y;
            wsum += w;
            uint4 hv = h16[(size_t)__float_as_int(p.x) * 8 + lq];
            a0 = fmaf(w, bflo(hv.x), a0); a1 = fmaf(w, bfhi(hv.x), a1);
            a2 = fmaf(w, bflo(hv.y), a2); a3 = fmaf(w, bfhi(hv.y), a3);
            a4 = fmaf(w, bflo(hv.z), a4); a5 = fmaf(w, bfhi(hv.z), a5);
            a6 = fmaf(w, bflo(hv.w), a6); a7 = fmaf(w, bfhi(hv.w), a7);
        }
        float inv = (s1 > s0) ? 1.f / wsum : 0.f;
        float4 o0 = make_float4(a0 * inv, a1 * inv, a2 * inv, a3 * inv);
        float4 o1 = make_float4(a4 * inv, a5 * inv, a6 * inv, a7 * inv);
        ((float4*)out)[(size_t)node * 16 + lq * 2 + 0] = o0;
        ((float4*)out)[(size_t)node * 16 + lq * 2 + 1] = o1;
    }
}

// ---------------- launch ----------------
extern "C" void kernel_launch(void* const* d_in, const int* in_sizes, int n_in,
                              void* d_out, int out_size, void* d_ws, size_t ws_size,
                              hipStream_t stream)
{
    const float* x     = (const float*)d_in[0];
    const int*   rows  = (const int*)d_in[1];
    const int*   cols  = (const int*)d_in[2];
    const float* W     = (const float*)d_in[3];
    const float* a_row = (const float*)d_in[4];
    const float* a_col = (const float*)d_in[5];
    float* out = (float*)d_out;

    char* ws = (char*)d_ws;
    size_t o = 0;
    unsigned short* h = (unsigned short*)(ws + o); o += (size_t)Nn * Dd * 2;  // 12.8 MB
    float* ar   = (float*)(ws + o); o += (size_t)Nn * 4;
    float* ac   = (float*)(ws + o); o += (size_t)Nn * 4;
    int*   bwp  = (int*)(ws + o);   o += 2048 * 4;
    unsigned int* binned = (unsigned int*)(ws + o); o += (size_t)NBK * BSLK * 4; // 12.8 MB

    bwp_init<<<7, 256, 0, stream>>>(bwp);
    bin_gemm<<<BINB + GEMB, 256, 0, stream>>>(rows, cols, bwp, binned,
                                              x, W, a_row, a_col, h, ar, ac);
    spmm_fused<<<NBK, 256, 0, stream>>>(binned, bwp, ar, ac, h, out);
}